// Round 4
// baseline (508.097 us; speedup 1.0000x reference)
//
#include <hip/hip_runtime.h>

// 6-layer MLP (1->64, 4x 64->64, 64->1), N=2,097,152 rows, fp32 in/out.
// Split-bf16 MFMA (hi+lo bf16 per fp32 operand, 3 MFMA per product term,
// fp32 accumulate) on v_mfma_f32_32x32x16_bf16.
//
// R4 changes vs R3 (which was VALU-epilogue-bound at 66% busy, 22% occ):
//  1. 512-thread blocks sharing one 64KB LDS weight image ->16 waves/CU.
//     __launch_bounds__(512,4) caps VGPR at 128 (R3 compiled to exactly 128).
//  2. log2e folding: prep scales W0,b0,biases by log2e and Wout by ln2.
//     Hidden W1..W4 pass through UNCHANGED (log2e*ln2=1): MFMA now emits
//     a' = a*log2e, so silu' = a'*rcp(1+exp2(-a')) -- v_exp gets a free
//     neg-modifier, no explicit *log2e mul anywhere.
//  3. Truncation split + v_perm_b32 packing: hi dword of two values in one
//     perm, lo = a - trunc(a) exact then perm-packed (err ~2^-16|a|).
//
// Layout algebra (verified C/D map: col=lane&31=batch, row=(r&3)+8(r>>2)+4h):
// D-slot (m,r,h) holds neuron nu = 32m+(r&3)+8(r>>2)+4h. Permuting layers
// 2..4 weight columns by g(k)=k with bits 2<->3 swapped makes the C->B
// transform in-register: B slot (s2,h,t) takes acc[m=s2>>1][r=2j+8(s2&1)(+1)]
// for t=2j(,2j+1). No shuffles, no barriers after staging.

typedef short short8 __attribute__((ext_vector_type(8)));
typedef float float16 __attribute__((ext_vector_type(16)));

// A-fragment strides in SHORTS: [L][s][m][part][lane][t]
#define T_STRIDE    8
#define PART_STRIDE (64 * T_STRIDE)          // 512
#define M_STRIDE    (2 * PART_STRIDE)        // 1024
#define S_STRIDE    (2 * M_STRIDE)           // 2048
#define L_STRIDE    (4 * S_STRIDE)           // 8192
#define A_TOTAL     (4 * L_STRIDE)           // 32768 shorts = 65536 B

// ws layout (bytes):
//   [0, 65536)       A-frags ushort[L=4][s=4][m=2][part=2][lane=64][t=8]
//   [65536, 66560)   biases*log2e  float[L=4][h=2][m=2][r=16]
//   [66560, 66816)   Wout*ln2      float[h=2][m=2][r=16]
//   [66816, 67072)   W0*log2e      float[64]
//   [67072, 67328)   b0*log2e      float[64]
#define WS_PB 65536
#define WS_PW 66560
#define WS_W0 66816
#define WS_B0 67072

#define LOG2E 1.44269504088896340736f
#define LN2   0.69314718055994530942f

union BFS { __bf16 b; unsigned short u; };
union FRAG { int4 i; short8 s; };

// silu in log2e-domain: input a' = a*log2e, output h' = h*log2e
__device__ __forceinline__ float silu_l2(float a) {
    float e = __builtin_amdgcn_exp2f(-a);          // v_exp_f32, neg is a modifier
    return a * __builtin_amdgcn_rcpf(1.0f + e);
}

// two values -> packed bf16 hi dword + lo dword (truncation split)
__device__ __forceinline__ void split_pair(float h0, float h1,
                                           unsigned& hid, unsigned& lod) {
    unsigned u0 = __builtin_bit_cast(unsigned, h0);
    unsigned u1 = __builtin_bit_cast(unsigned, h1);
    hid = __builtin_amdgcn_perm(u1, u0, 0x07060302u);  // [hi16(u1) | hi16(u0)]
    float t0 = __builtin_bit_cast(float, u0 & 0xFFFF0000u);
    float t1 = __builtin_bit_cast(float, u1 & 0xFFFF0000u);
    float l0 = h0 - t0;                                 // exact
    float l1 = h1 - t1;
    lod = __builtin_amdgcn_perm(__builtin_bit_cast(unsigned, l1),
                                __builtin_bit_cast(unsigned, l0), 0x07060302u);
}

// ---------------- prep kernel ---------------------------------------------
__global__ void prep_kernel(const float* __restrict__ W0, const float* __restrict__ b0,
                            const float* __restrict__ W1, const float* __restrict__ W2,
                            const float* __restrict__ W3, const float* __restrict__ W4,
                            const float* __restrict__ b1, const float* __restrict__ b2,
                            const float* __restrict__ b3, const float* __restrict__ b4,
                            const float* __restrict__ Wout,
                            unsigned char* __restrict__ ws)
{
    unsigned short* A = (unsigned short*)ws;
    float* PB  = (float*)(ws + WS_PB);
    float* PW  = (float*)(ws + WS_PW);
    float* PW0 = (float*)(ws + WS_W0);
    float* PB0 = (float*)(ws + WS_B0);
    int tid = blockIdx.x * blockDim.x + threadIdx.x;
    int stride = gridDim.x * blockDim.x;

    const float* Ws[4] = {W1, W2, W3, W4};
    const float* bs[4] = {b1, b2, b3, b4};

    // A-fragments (weights UNCHANGED numerically; log2e folding cancels)
    for (int i = tid; i < 4 * 4 * 2 * 64; i += stride) {
        int L = i >> 9, s = (i >> 7) & 3, m = (i >> 6) & 1, lane = i & 63;
        int h = lane >> 5;
        int n = m * 32 + (lane & 31);
        const float* W = Ws[L];
        unsigned short* dh = A + L * L_STRIDE + s * S_STRIDE + m * M_STRIDE
                               + 0 * PART_STRIDE + lane * T_STRIDE;
        unsigned short* dl = A + L * L_STRIDE + s * S_STRIDE + m * M_STRIDE
                               + 1 * PART_STRIDE + lane * T_STRIDE;
        for (int t = 0; t < 8; ++t) {
            int k = s * 16 + h * 8 + t;
            int col = (L == 0) ? k : ((k & ~12) | ((k & 4) << 1) | ((k & 8) >> 1));
            float val = W[n * 64 + col];
            BFS hb; hb.b = (__bf16)val;
            float hf = (float)hb.b;
            BFS lb; lb.b = (__bf16)(val - hf);
            dh[t] = hb.u;
            dl[t] = lb.u;
        }
    }

    // biases at D-slot order, scaled by log2e
    for (int i = tid; i < 4 * 2 * 2 * 16; i += stride) {
        int L = i >> 6, h = (i >> 5) & 1, m = (i >> 4) & 1, r = i & 15;
        int nu = 32 * m + (r & 3) + 8 * (r >> 2) + 4 * h;
        PB[i] = bs[L][nu] * LOG2E;
    }
    // Wout at D-slot order, scaled by ln2 (activations carry a log2e factor)
    for (int i = tid; i < 2 * 2 * 16; i += stride) {
        int h = (i >> 5) & 1, m = (i >> 4) & 1, r = i & 15;
        int nu = 32 * m + (r & 3) + 8 * (r >> 2) + 4 * h;
        PW[i] = Wout[nu] * LN2;
    }
    // layer0 params scaled by log2e
    for (int i = tid; i < 64; i += stride) {
        PW0[i] = W0[i] * LOG2E;
        PB0[i] = b0[i] * LOG2E;
    }
}

// ---------------- main kernel ---------------------------------------------
__global__ __launch_bounds__(512, 4) void mlp_mfma(
    const float* __restrict__ x, const float* __restrict__ bout,
    const unsigned char* __restrict__ ws, float* __restrict__ out)
{
    __shared__ unsigned short ldsA[A_TOTAL];  // 64 KB, shared by 8 waves

    const int tid = threadIdx.x;
    {
        const int4* src = (const int4*)ws;
        int4* dst = (int4*)ldsA;
#pragma unroll
        for (int i = 0; i < 8; ++i) dst[tid + i * 512] = src[tid + i * 512];
    }
    __syncthreads();

    const float* PB  = (const float*)(ws + WS_PB);
    const float* PW  = (const float*)(ws + WS_PW);
    const float* PW0 = (const float*)(ws + WS_W0);
    const float* PB0 = (const float*)(ws + WS_B0);

    const int lane = tid & 63;
    const int wv = tid >> 6;           // 0..7
    const int h = lane >> 5;
    const int lr = lane & 31;
    const int rowbase = blockIdx.x * 512 + wv * 64;

    const float xv0 = x[rowbase + lr];
    const float xv1 = x[rowbase + 32 + lr];

    FRAG Bhi[2][4], Blo[2][4];

    // ---- layer 0: 1 -> 64 in log2e-domain, produced in B-frag layout.
#pragma unroll
    for (int s = 0; s < 4; ++s) {
        float w0t[8], b0t[8];
        *(float4*)&w0t[0] = *(const float4*)(PW0 + s * 16 + h * 8);
        *(float4*)&w0t[4] = *(const float4*)(PW0 + s * 16 + h * 8 + 4);
        *(float4*)&b0t[0] = *(const float4*)(PB0 + s * 16 + h * 8);
        *(float4*)&b0t[4] = *(const float4*)(PB0 + s * 16 + h * 8 + 4);
#pragma unroll
        for (int j = 0; j < 4; ++j) {
            float a00 = silu_l2(fmaf(xv0, w0t[2 * j], b0t[2 * j]));
            float a01 = silu_l2(fmaf(xv0, w0t[2 * j + 1], b0t[2 * j + 1]));
            float a10 = silu_l2(fmaf(xv1, w0t[2 * j], b0t[2 * j]));
            float a11 = silu_l2(fmaf(xv1, w0t[2 * j + 1], b0t[2 * j + 1]));
            unsigned hd, ld;
            split_pair(a00, a01, hd, ld);
            Bhi[0][s].i[j] = (int)hd; Blo[0][s].i[j] = (int)ld;
            split_pair(a10, a11, hd, ld);
            Bhi[1][s].i[j] = (int)hd; Blo[1][s].i[j] = (int)ld;
        }
    }

    // ---- layers 1..4
    float16 acc[2][2];
    for (int L = 0; L < 4; ++L) {
        const float* pb0 = PB + ((L * 2 + h) * 2 + 0) * 16;
        const float* pb1 = PB + ((L * 2 + h) * 2 + 1) * 16;
#pragma unroll
        for (int r = 0; r < 16; ++r) {
            float v0 = pb0[r], v1 = pb1[r];
            acc[0][0][r] = v0; acc[1][0][r] = v0;
            acc[0][1][r] = v1; acc[1][1][r] = v1;
        }

        const unsigned short* aL = ldsA + L * L_STRIDE;
#pragma unroll
        for (int s = 0; s < 4; ++s) {
            const unsigned short* base = aL + s * S_STRIDE;
            short8 ah0 = *(const short8*)(base + 0 * M_STRIDE + 0 * PART_STRIDE + lane * T_STRIDE);
            short8 al0 = *(const short8*)(base + 0 * M_STRIDE + 1 * PART_STRIDE + lane * T_STRIDE);
            short8 ah1 = *(const short8*)(base + 1 * M_STRIDE + 0 * PART_STRIDE + lane * T_STRIDE);
            short8 al1 = *(const short8*)(base + 1 * M_STRIDE + 1 * PART_STRIDE + lane * T_STRIDE);
            acc[0][0] = __builtin_amdgcn_mfma_f32_32x32x16_bf16(ah0, Bhi[0][s].s, acc[0][0], 0, 0, 0);
            acc[0][1] = __builtin_amdgcn_mfma_f32_32x32x16_bf16(ah1, Bhi[0][s].s, acc[0][1], 0, 0, 0);
            acc[1][0] = __builtin_amdgcn_mfma_f32_32x32x16_bf16(ah0, Bhi[1][s].s, acc[1][0], 0, 0, 0);
            acc[1][1] = __builtin_amdgcn_mfma_f32_32x32x16_bf16(ah1, Bhi[1][s].s, acc[1][1], 0, 0, 0);
            acc[0][0] = __builtin_amdgcn_mfma_f32_32x32x16_bf16(ah0, Blo[0][s].s, acc[0][0], 0, 0, 0);
            acc[0][1] = __builtin_amdgcn_mfma_f32_32x32x16_bf16(ah1, Blo[0][s].s, acc[0][1], 0, 0, 0);
            acc[1][0] = __builtin_amdgcn_mfma_f32_32x32x16_bf16(ah0, Blo[1][s].s, acc[1][0], 0, 0, 0);
            acc[1][1] = __builtin_amdgcn_mfma_f32_32x32x16_bf16(ah1, Blo[1][s].s, acc[1][1], 0, 0, 0);
            acc[0][0] = __builtin_amdgcn_mfma_f32_32x32x16_bf16(al0, Bhi[0][s].s, acc[0][0], 0, 0, 0);
            acc[0][1] = __builtin_amdgcn_mfma_f32_32x32x16_bf16(al1, Bhi[0][s].s, acc[0][1], 0, 0, 0);
            acc[1][0] = __builtin_amdgcn_mfma_f32_32x32x16_bf16(al0, Bhi[1][s].s, acc[1][0], 0, 0, 0);
            acc[1][1] = __builtin_amdgcn_mfma_f32_32x32x16_bf16(al1, Bhi[1][s].s, acc[1][1], 0, 0, 0);
        }

        if (L < 3) {
            // in-place C->B: B slot (s2,h,t=2j,2j+1) <- acc[ct][s2>>1][2j+8(s2&1)(+1)]
#pragma unroll
            for (int ct = 0; ct < 2; ++ct) {
#pragma unroll
                for (int s2 = 0; s2 < 4; ++s2) {
                    const int m = s2 >> 1;
                    const int rb = 8 * (s2 & 1);
#pragma unroll
                    for (int j = 0; j < 4; ++j) {
                        float h0 = silu_l2(acc[ct][m][rb + 2 * j]);
                        float h1 = silu_l2(acc[ct][m][rb + 2 * j + 1]);
                        unsigned hd, ld;
                        split_pair(h0, h1, hd, ld);
                        Bhi[ct][s2].i[j] = (int)hd;
                        Blo[ct][s2].i[j] = (int)ld;
                    }
                }
            }
        } else {
            const float* pw0 = PW + (h * 2 + 0) * 16;
            const float* pw1 = PW + (h * 2 + 1) * 16;
            float dot0 = 0.0f, dot1 = 0.0f;
#pragma unroll
            for (int r = 0; r < 16; ++r) {
                float w0v = pw0[r], w1v = pw1[r];
                dot0 = fmaf(silu_l2(acc[0][0][r]), w0v, dot0);
                dot0 = fmaf(silu_l2(acc[0][1][r]), w1v, dot0);
                dot1 = fmaf(silu_l2(acc[1][0][r]), w0v, dot1);
                dot1 = fmaf(silu_l2(acc[1][1][r]), w1v, dot1);
            }
            dot0 += __shfl_xor(dot0, 32);
            dot1 += __shfl_xor(dot1, 32);
            float bo = bout[0];
            if (h == 0) {
                out[rowbase + lr] = dot0 + bo;
                out[rowbase + 32 + lr] = dot1 + bo;
            }
        }
    }
}

extern "C" void kernel_launch(void* const* d_in, const int* in_sizes, int n_in,
                              void* d_out, int out_size, void* d_ws, size_t ws_size,
                              hipStream_t stream) {
    const float* x    = (const float*)d_in[0];
    const float* W0   = (const float*)d_in[1];
    const float* b0   = (const float*)d_in[2];
    const float* W1   = (const float*)d_in[3];
    const float* b1   = (const float*)d_in[4];
    const float* W2   = (const float*)d_in[5];
    const float* b2   = (const float*)d_in[6];
    const float* W3   = (const float*)d_in[7];
    const float* b3   = (const float*)d_in[8];
    const float* W4   = (const float*)d_in[9];
    const float* b4   = (const float*)d_in[10];
    const float* Wout = (const float*)d_in[11];
    const float* bout = (const float*)d_in[12];
    float* out = (float*)d_out;

    int n = in_sizes[0];  // 2,097,152 (divisible by 512)

    prep_kernel<<<16, 256, 0, stream>>>(W0, b0, W1, W2, W3, W4,
                                        b1, b2, b3, b4, Wout,
                                        (unsigned char*)d_ws);
    mlp_mfma<<<n / 512, 512, 0, stream>>>(x, bout,
                                          (const unsigned char*)d_ws, out);
}

// Round 5
// 358.304 us; speedup vs baseline: 1.4181x; 1.4181x over previous
//
#include <hip/hip_runtime.h>

// 6-layer MLP (1->64, 4x 64->64, 64->1), N=2,097,152 rows, fp32 in/out.
// Split-bf16 MFMA (hi+lo bf16 per fp32 operand, 3 MFMA per product term,
// fp32 accumulate) on v_mfma_f32_32x32x16_bf16.
//
// R5 vs R4: R4's __launch_bounds__(512,4) = 128 TOTAL regs (unified
// VGPR+AGPR on gfx950); acc alone is 64 AGPR -> massive scratch spill
// (WRITE_SIZE 754 MB, scratch-BW-bound). Fix: 384-thr blocks (6 waves),
// __launch_bounds__(384,3): 2 blocks/CU (128 KB LDS), 12 waves/CU,
// reg cap 170 total = ~106 arch + 64 acc. Epilogue unchanged from R4
// (log2e folding + perm truncation split, absmax 2.44e-4 validated).
//
// Layout algebra (verified C/D map: col=lane&31=batch, row=(r&3)+8(r>>2)+4h):
// D-slot (m,r,h) holds neuron nu = 32m+(r&3)+8(r>>2)+4h. Permuting layers
// 2..4 weight columns by g(k)=k with bits 2<->3 swapped makes the C->B
// transform in-register: B slot (s2,h,t=2j,2j+1) <- acc[s2>>1][2j+8(s2&1)(+1)].
// No shuffles, no barriers after staging.

typedef short short8 __attribute__((ext_vector_type(8)));
typedef float float16 __attribute__((ext_vector_type(16)));

// A-fragment strides in SHORTS: [L][s][m][part][lane][t]
#define T_STRIDE    8
#define PART_STRIDE (64 * T_STRIDE)          // 512
#define M_STRIDE    (2 * PART_STRIDE)        // 1024
#define S_STRIDE    (2 * M_STRIDE)           // 2048
#define L_STRIDE    (4 * S_STRIDE)           // 8192
#define A_TOTAL     (4 * L_STRIDE)           // 32768 shorts = 65536 B

// ws layout (bytes):
#define WS_PB 65536
#define WS_PW 66560
#define WS_W0 66816
#define WS_B0 67072

#define LOG2E 1.44269504088896340736f
#define LN2   0.69314718055994530942f

union BFS { __bf16 b; unsigned short u; };
union FRAG { int4 i; short8 s; };

// silu in log2e-domain: input a' = a*log2e, output h' = h*log2e
__device__ __forceinline__ float silu_l2(float a) {
    float e = __builtin_amdgcn_exp2f(-a);          // v_exp_f32, neg is a modifier
    return a * __builtin_amdgcn_rcpf(1.0f + e);
}

// two values -> packed bf16 hi dword + lo dword (truncation split)
__device__ __forceinline__ void split_pair(float h0, float h1,
                                           unsigned& hid, unsigned& lod) {
    unsigned u0 = __builtin_bit_cast(unsigned, h0);
    unsigned u1 = __builtin_bit_cast(unsigned, h1);
    hid = __builtin_amdgcn_perm(u1, u0, 0x07060302u);  // [hi16(u1) | hi16(u0)]
    float t0 = __builtin_bit_cast(float, u0 & 0xFFFF0000u);
    float t1 = __builtin_bit_cast(float, u1 & 0xFFFF0000u);
    float l0 = h0 - t0;                                 // exact
    float l1 = h1 - t1;
    lod = __builtin_amdgcn_perm(__builtin_bit_cast(unsigned, l1),
                                __builtin_bit_cast(unsigned, l0), 0x07060302u);
}

// ---------------- prep kernel ---------------------------------------------
__global__ void prep_kernel(const float* __restrict__ W0, const float* __restrict__ b0,
                            const float* __restrict__ W1, const float* __restrict__ W2,
                            const float* __restrict__ W3, const float* __restrict__ W4,
                            const float* __restrict__ b1, const float* __restrict__ b2,
                            const float* __restrict__ b3, const float* __restrict__ b4,
                            const float* __restrict__ Wout,
                            unsigned char* __restrict__ ws)
{
    unsigned short* A = (unsigned short*)ws;
    float* PB  = (float*)(ws + WS_PB);
    float* PW  = (float*)(ws + WS_PW);
    float* PW0 = (float*)(ws + WS_W0);
    float* PB0 = (float*)(ws + WS_B0);
    int tid = blockIdx.x * blockDim.x + threadIdx.x;
    int stride = gridDim.x * blockDim.x;

    const float* Ws[4] = {W1, W2, W3, W4};
    const float* bs[4] = {b1, b2, b3, b4};

    // A-fragments (weights UNCHANGED numerically; log2e folding cancels)
    for (int i = tid; i < 4 * 4 * 2 * 64; i += stride) {
        int L = i >> 9, s = (i >> 7) & 3, m = (i >> 6) & 1, lane = i & 63;
        int h = lane >> 5;
        int n = m * 32 + (lane & 31);
        const float* W = Ws[L];
        unsigned short* dh = A + L * L_STRIDE + s * S_STRIDE + m * M_STRIDE
                               + 0 * PART_STRIDE + lane * T_STRIDE;
        unsigned short* dl = A + L * L_STRIDE + s * S_STRIDE + m * M_STRIDE
                               + 1 * PART_STRIDE + lane * T_STRIDE;
        for (int t = 0; t < 8; ++t) {
            int k = s * 16 + h * 8 + t;
            int col = (L == 0) ? k : ((k & ~12) | ((k & 4) << 1) | ((k & 8) >> 1));
            float val = W[n * 64 + col];
            BFS hb; hb.b = (__bf16)val;
            float hf = (float)hb.b;
            BFS lb; lb.b = (__bf16)(val - hf);
            dh[t] = hb.u;
            dl[t] = lb.u;
        }
    }

    // biases at D-slot order, scaled by log2e
    for (int i = tid; i < 4 * 2 * 2 * 16; i += stride) {
        int L = i >> 6, h = (i >> 5) & 1, m = (i >> 4) & 1, r = i & 15;
        int nu = 32 * m + (r & 3) + 8 * (r >> 2) + 4 * h;
        PB[i] = bs[L][nu] * LOG2E;
    }
    // Wout at D-slot order, scaled by ln2 (activations carry a log2e factor)
    for (int i = tid; i < 2 * 2 * 16; i += stride) {
        int h = (i >> 5) & 1, m = (i >> 4) & 1, r = i & 15;
        int nu = 32 * m + (r & 3) + 8 * (r >> 2) + 4 * h;
        PW[i] = Wout[nu] * LN2;
    }
    // layer0 params scaled by log2e
    for (int i = tid; i < 64; i += stride) {
        PW0[i] = W0[i] * LOG2E;
        PB0[i] = b0[i] * LOG2E;
    }
}

// ---------------- main kernel ---------------------------------------------
// 384 threads = 6 waves; 2 blocks/CU (128 KB LDS); 3 waves/EU -> 170-reg cap.
__global__ __launch_bounds__(384, 3) void mlp_mfma(
    const float* __restrict__ x, const float* __restrict__ bout,
    const unsigned char* __restrict__ ws, float* __restrict__ out, int n)
{
    __shared__ unsigned short ldsA[A_TOTAL];  // 64 KB, shared by 6 waves

    const int tid = threadIdx.x;
    {
        const int4* src = (const int4*)ws;
        int4* dst = (int4*)ldsA;
#pragma unroll
        for (int i = 0; i < 11; ++i) {
            int idx = tid + i * 384;
            if (idx < 4096) dst[idx] = src[idx];
        }
    }
    __syncthreads();

    const float* PB  = (const float*)(ws + WS_PB);
    const float* PW  = (const float*)(ws + WS_PW);
    const float* PW0 = (const float*)(ws + WS_W0);
    const float* PB0 = (const float*)(ws + WS_B0);

    const int lane = tid & 63;
    const int wv = tid >> 6;           // 0..5
    const int h = lane >> 5;
    const int lr = lane & 31;
    const int rowbase = blockIdx.x * 384 + wv * 64;
    const int row0 = rowbase + lr;
    const int row1 = rowbase + 32 + lr;

    const float xv0 = (row0 < n) ? x[row0] : 0.0f;
    const float xv1 = (row1 < n) ? x[row1] : 0.0f;

    FRAG Bhi[2][4], Blo[2][4];

    // ---- layer 0: 1 -> 64 in log2e-domain, produced in B-frag layout.
#pragma unroll
    for (int s = 0; s < 4; ++s) {
        float w0t[8], b0t[8];
        *(float4*)&w0t[0] = *(const float4*)(PW0 + s * 16 + h * 8);
        *(float4*)&w0t[4] = *(const float4*)(PW0 + s * 16 + h * 8 + 4);
        *(float4*)&b0t[0] = *(const float4*)(PB0 + s * 16 + h * 8);
        *(float4*)&b0t[4] = *(const float4*)(PB0 + s * 16 + h * 8 + 4);
#pragma unroll
        for (int j = 0; j < 4; ++j) {
            float a00 = silu_l2(fmaf(xv0, w0t[2 * j], b0t[2 * j]));
            float a01 = silu_l2(fmaf(xv0, w0t[2 * j + 1], b0t[2 * j + 1]));
            float a10 = silu_l2(fmaf(xv1, w0t[2 * j], b0t[2 * j]));
            float a11 = silu_l2(fmaf(xv1, w0t[2 * j + 1], b0t[2 * j + 1]));
            unsigned hd, ld;
            split_pair(a00, a01, hd, ld);
            Bhi[0][s].i[j] = (int)hd; Blo[0][s].i[j] = (int)ld;
            split_pair(a10, a11, hd, ld);
            Bhi[1][s].i[j] = (int)hd; Blo[1][s].i[j] = (int)ld;
        }
    }

    // ---- layers 1..4
    float16 acc[2][2];
    for (int L = 0; L < 4; ++L) {
        const float* pb0 = PB + ((L * 2 + h) * 2 + 0) * 16;
        const float* pb1 = PB + ((L * 2 + h) * 2 + 1) * 16;
#pragma unroll
        for (int r = 0; r < 16; ++r) {
            float v0 = pb0[r], v1 = pb1[r];
            acc[0][0][r] = v0; acc[1][0][r] = v0;
            acc[0][1][r] = v1; acc[1][1][r] = v1;
        }

        const unsigned short* aL = ldsA + L * L_STRIDE;
#pragma unroll
        for (int s = 0; s < 4; ++s) {
            const unsigned short* base = aL + s * S_STRIDE;
            short8 ah0 = *(const short8*)(base + 0 * M_STRIDE + 0 * PART_STRIDE + lane * T_STRIDE);
            short8 al0 = *(const short8*)(base + 0 * M_STRIDE + 1 * PART_STRIDE + lane * T_STRIDE);
            short8 ah1 = *(const short8*)(base + 1 * M_STRIDE + 0 * PART_STRIDE + lane * T_STRIDE);
            short8 al1 = *(const short8*)(base + 1 * M_STRIDE + 1 * PART_STRIDE + lane * T_STRIDE);
            acc[0][0] = __builtin_amdgcn_mfma_f32_32x32x16_bf16(ah0, Bhi[0][s].s, acc[0][0], 0, 0, 0);
            acc[0][1] = __builtin_amdgcn_mfma_f32_32x32x16_bf16(ah1, Bhi[0][s].s, acc[0][1], 0, 0, 0);
            acc[1][0] = __builtin_amdgcn_mfma_f32_32x32x16_bf16(ah0, Bhi[1][s].s, acc[1][0], 0, 0, 0);
            acc[1][1] = __builtin_amdgcn_mfma_f32_32x32x16_bf16(ah1, Bhi[1][s].s, acc[1][1], 0, 0, 0);
            acc[0][0] = __builtin_amdgcn_mfma_f32_32x32x16_bf16(ah0, Blo[0][s].s, acc[0][0], 0, 0, 0);
            acc[0][1] = __builtin_amdgcn_mfma_f32_32x32x16_bf16(ah1, Blo[0][s].s, acc[0][1], 0, 0, 0);
            acc[1][0] = __builtin_amdgcn_mfma_f32_32x32x16_bf16(ah0, Blo[1][s].s, acc[1][0], 0, 0, 0);
            acc[1][1] = __builtin_amdgcn_mfma_f32_32x32x16_bf16(ah1, Blo[1][s].s, acc[1][1], 0, 0, 0);
            acc[0][0] = __builtin_amdgcn_mfma_f32_32x32x16_bf16(al0, Bhi[0][s].s, acc[0][0], 0, 0, 0);
            acc[0][1] = __builtin_amdgcn_mfma_f32_32x32x16_bf16(al1, Bhi[0][s].s, acc[0][1], 0, 0, 0);
            acc[1][0] = __builtin_amdgcn_mfma_f32_32x32x16_bf16(al0, Bhi[1][s].s, acc[1][0], 0, 0, 0);
            acc[1][1] = __builtin_amdgcn_mfma_f32_32x32x16_bf16(al1, Bhi[1][s].s, acc[1][1], 0, 0, 0);
        }

        if (L < 3) {
            // in-place C->B: B slot (s2,h,t=2j,2j+1) <- acc[ct][s2>>1][2j+8(s2&1)(+1)]
#pragma unroll
            for (int ct = 0; ct < 2; ++ct) {
#pragma unroll
                for (int s2 = 0; s2 < 4; ++s2) {
                    const int m = s2 >> 1;
                    const int rb = 8 * (s2 & 1);
#pragma unroll
                    for (int j = 0; j < 4; ++j) {
                        float h0 = silu_l2(acc[ct][m][rb + 2 * j]);
                        float h1 = silu_l2(acc[ct][m][rb + 2 * j + 1]);
                        unsigned hd, ld;
                        split_pair(h0, h1, hd, ld);
                        Bhi[ct][s2].i[j] = (int)hd;
                        Blo[ct][s2].i[j] = (int)ld;
                    }
                }
            }
        } else {
            const float* pw0 = PW + (h * 2 + 0) * 16;
            const float* pw1 = PW + (h * 2 + 1) * 16;
            float dot0 = 0.0f, dot1 = 0.0f;
#pragma unroll
            for (int r = 0; r < 16; ++r) {
                float w0v = pw0[r], w1v = pw1[r];
                dot0 = fmaf(silu_l2(acc[0][0][r]), w0v, dot0);
                dot0 = fmaf(silu_l2(acc[0][1][r]), w1v, dot0);
                dot1 = fmaf(silu_l2(acc[1][0][r]), w0v, dot1);
                dot1 = fmaf(silu_l2(acc[1][1][r]), w1v, dot1);
            }
            dot0 += __shfl_xor(dot0, 32);
            dot1 += __shfl_xor(dot1, 32);
            float bo = bout[0];
            if (h == 0) {
                if (row0 < n) out[row0] = dot0 + bo;
                if (row1 < n) out[row1] = dot1 + bo;
            }
        }
    }
}

extern "C" void kernel_launch(void* const* d_in, const int* in_sizes, int n_in,
                              void* d_out, int out_size, void* d_ws, size_t ws_size,
                              hipStream_t stream) {
    const float* x    = (const float*)d_in[0];
    const float* W0   = (const float*)d_in[1];
    const float* b0   = (const float*)d_in[2];
    const float* W1   = (const float*)d_in[3];
    const float* b1   = (const float*)d_in[4];
    const float* W2   = (const float*)d_in[5];
    const float* b2   = (const float*)d_in[6];
    const float* W3   = (const float*)d_in[7];
    const float* b3   = (const float*)d_in[8];
    const float* W4   = (const float*)d_in[9];
    const float* b4   = (const float*)d_in[10];
    const float* Wout = (const float*)d_in[11];
    const float* bout = (const float*)d_in[12];
    float* out = (float*)d_out;

    int n = in_sizes[0];  // 2,097,152
    int grid = (n + 383) / 384;

    prep_kernel<<<16, 256, 0, stream>>>(W0, b0, W1, W2, W3, W4,
                                        b1, b2, b3, b4, Wout,
                                        (unsigned char*)d_ws);
    mlp_mfma<<<grid, 384, 0, stream>>>(x, bout,
                                       (const unsigned char*)d_ws, out, n);
}

// Round 6
// 317.897 us; speedup vs baseline: 1.5983x; 1.1271x over previous
//
#include <hip/hip_runtime.h>

// 6-layer MLP (1->64, 4x 64->64, 64->1), N=2,097,152 rows, fp32 in/out.
// Split-bf16 MFMA (hi+lo bf16 per fp32 operand, 3 MFMA per product term,
// fp32 accumulate) on v_mfma_f32_32x32x16_bf16.
//
// R6 vs R5: R5 hit the 128->256 register-allocation quantum (148 total regs
// -> 2 waves/SIMD -> 6 waves/CU, 17.8% occ). Fix: ONE col-tile (32 rows) per
// wave: acc 64->32 AGPR, B-frags 32->16 VGPR; __launch_bounds__(512,4) caps
// at 128 total = 4 waves/SIMD. 512-thr blocks (8 waves) x 64KB LDS -> 2
// blocks/CU -> 16 waves/CU (50%). MFMA work per row unchanged.
// Epilogue unchanged from R4/R5 (log2e folding + perm truncation split).
//
// Layout algebra (verified C/D map: col=lane&31=batch, row=(r&3)+8(r>>2)+4h):
// D-slot (m,r,h) holds neuron nu = 32m+(r&3)+8(r>>2)+4h. Permuting layers
// 2..4 weight columns by g(k)=k with bits 2<->3 swapped makes the C->B
// transform in-register: B slot (s2,h,t=2j,2j+1) <- acc[s2>>1][2j+8(s2&1)(+1)].
// No shuffles, no barriers after staging.

typedef short short8 __attribute__((ext_vector_type(8)));
typedef float float16 __attribute__((ext_vector_type(16)));

// A-fragment strides in SHORTS: [L][s][m][part][lane][t]
#define T_STRIDE    8
#define PART_STRIDE (64 * T_STRIDE)          // 512
#define M_STRIDE    (2 * PART_STRIDE)        // 1024
#define S_STRIDE    (2 * M_STRIDE)           // 2048
#define L_STRIDE    (4 * S_STRIDE)           // 8192
#define A_TOTAL     (4 * L_STRIDE)           // 32768 shorts = 65536 B

// ws layout (bytes):
#define WS_PB 65536
#define WS_PW 66560
#define WS_W0 66816
#define WS_B0 67072

#define LOG2E 1.44269504088896340736f
#define LN2   0.69314718055994530942f

union BFS { __bf16 b; unsigned short u; };
union FRAG { int4 i; short8 s; };

// silu in log2e-domain: input a' = a*log2e, output h' = h*log2e
__device__ __forceinline__ float silu_l2(float a) {
    float e = __builtin_amdgcn_exp2f(-a);          // v_exp_f32, neg is a modifier
    return a * __builtin_amdgcn_rcpf(1.0f + e);
}

// two values -> packed bf16 hi dword + lo dword (truncation split)
__device__ __forceinline__ void split_pair(float h0, float h1,
                                           unsigned& hid, unsigned& lod) {
    unsigned u0 = __builtin_bit_cast(unsigned, h0);
    unsigned u1 = __builtin_bit_cast(unsigned, h1);
    hid = __builtin_amdgcn_perm(u1, u0, 0x07060302u);  // [hi16(u1) | hi16(u0)]
    float t0 = __builtin_bit_cast(float, u0 & 0xFFFF0000u);
    float t1 = __builtin_bit_cast(float, u1 & 0xFFFF0000u);
    float l0 = h0 - t0;                                 // exact
    float l1 = h1 - t1;
    lod = __builtin_amdgcn_perm(__builtin_bit_cast(unsigned, l1),
                                __builtin_bit_cast(unsigned, l0), 0x07060302u);
}

// ---------------- prep kernel ---------------------------------------------
__global__ void prep_kernel(const float* __restrict__ W0, const float* __restrict__ b0,
                            const float* __restrict__ W1, const float* __restrict__ W2,
                            const float* __restrict__ W3, const float* __restrict__ W4,
                            const float* __restrict__ b1, const float* __restrict__ b2,
                            const float* __restrict__ b3, const float* __restrict__ b4,
                            const float* __restrict__ Wout,
                            unsigned char* __restrict__ ws)
{
    unsigned short* A = (unsigned short*)ws;
    float* PB  = (float*)(ws + WS_PB);
    float* PW  = (float*)(ws + WS_PW);
    float* PW0 = (float*)(ws + WS_W0);
    float* PB0 = (float*)(ws + WS_B0);
    int tid = blockIdx.x * blockDim.x + threadIdx.x;
    int stride = gridDim.x * blockDim.x;

    const float* Ws[4] = {W1, W2, W3, W4};
    const float* bs[4] = {b1, b2, b3, b4};

    // A-fragments (weights UNCHANGED numerically; log2e folding cancels)
    for (int i = tid; i < 4 * 4 * 2 * 64; i += stride) {
        int L = i >> 9, s = (i >> 7) & 3, m = (i >> 6) & 1, lane = i & 63;
        int h = lane >> 5;
        int n = m * 32 + (lane & 31);
        const float* W = Ws[L];
        unsigned short* dh = A + L * L_STRIDE + s * S_STRIDE + m * M_STRIDE
                               + 0 * PART_STRIDE + lane * T_STRIDE;
        unsigned short* dl = A + L * L_STRIDE + s * S_STRIDE + m * M_STRIDE
                               + 1 * PART_STRIDE + lane * T_STRIDE;
        for (int t = 0; t < 8; ++t) {
            int k = s * 16 + h * 8 + t;
            int col = (L == 0) ? k : ((k & ~12) | ((k & 4) << 1) | ((k & 8) >> 1));
            float val = W[n * 64 + col];
            BFS hb; hb.b = (__bf16)val;
            float hf = (float)hb.b;
            BFS lb; lb.b = (__bf16)(val - hf);
            dh[t] = hb.u;
            dl[t] = lb.u;
        }
    }

    // biases at D-slot order, scaled by log2e
    for (int i = tid; i < 4 * 2 * 2 * 16; i += stride) {
        int L = i >> 6, h = (i >> 5) & 1, m = (i >> 4) & 1, r = i & 15;
        int nu = 32 * m + (r & 3) + 8 * (r >> 2) + 4 * h;
        PB[i] = bs[L][nu] * LOG2E;
    }
    // Wout at D-slot order, scaled by ln2 (activations carry a log2e factor)
    for (int i = tid; i < 2 * 2 * 16; i += stride) {
        int h = (i >> 5) & 1, m = (i >> 4) & 1, r = i & 15;
        int nu = 32 * m + (r & 3) + 8 * (r >> 2) + 4 * h;
        PW[i] = Wout[nu] * LN2;
    }
    // layer0 params scaled by log2e
    for (int i = tid; i < 64; i += stride) {
        PW0[i] = W0[i] * LOG2E;
        PB0[i] = b0[i] * LOG2E;
    }
}

// ---------------- main kernel ---------------------------------------------
// 512 threads = 8 waves, 32 rows/wave (one 32-col tile); 2 blocks/CU
// (128 KB LDS); __launch_bounds__(512,4) -> 128 total regs -> 4 waves/SIMD.
__global__ __launch_bounds__(512, 4) void mlp_mfma(
    const float* __restrict__ x, const float* __restrict__ bout,
    const unsigned char* __restrict__ ws, float* __restrict__ out, int n)
{
    __shared__ unsigned short ldsA[A_TOTAL];  // 64 KB, shared by 8 waves

    const int tid = threadIdx.x;
    {
        const int4* src = (const int4*)ws;
        int4* dst = (int4*)ldsA;
#pragma unroll
        for (int i = 0; i < 8; ++i) dst[tid + i * 512] = src[tid + i * 512];
    }
    __syncthreads();

    const float* PB  = (const float*)(ws + WS_PB);
    const float* PW  = (const float*)(ws + WS_PW);
    const float* PW0 = (const float*)(ws + WS_W0);
    const float* PB0 = (const float*)(ws + WS_B0);

    const int lane = tid & 63;
    const int wv = tid >> 6;           // 0..7
    const int h = lane >> 5;
    const int lr = lane & 31;
    const int row = blockIdx.x * 256 + wv * 32 + lr;

    const float xv = (row < n) ? x[row] : 0.0f;

    FRAG Bhi[4], Blo[4];

    // ---- layer 0: 1 -> 64 in log2e-domain, produced in B-frag layout.
    // B slot (s,h,t) holds neuron k = 16s + 8h + t for batch row `row`.
#pragma unroll
    for (int s = 0; s < 4; ++s) {
        float w0t[8], b0t[8];
        *(float4*)&w0t[0] = *(const float4*)(PW0 + s * 16 + h * 8);
        *(float4*)&w0t[4] = *(const float4*)(PW0 + s * 16 + h * 8 + 4);
        *(float4*)&b0t[0] = *(const float4*)(PB0 + s * 16 + h * 8);
        *(float4*)&b0t[4] = *(const float4*)(PB0 + s * 16 + h * 8 + 4);
#pragma unroll
        for (int j = 0; j < 4; ++j) {
            float a0 = silu_l2(fmaf(xv, w0t[2 * j], b0t[2 * j]));
            float a1 = silu_l2(fmaf(xv, w0t[2 * j + 1], b0t[2 * j + 1]));
            unsigned hd, ld;
            split_pair(a0, a1, hd, ld);
            Bhi[s].i[j] = (int)hd;
            Blo[s].i[j] = (int)ld;
        }
    }

    // ---- layers 1..4
    float16 acc[2];
    for (int L = 0; L < 4; ++L) {
        const float* pb0 = PB + ((L * 2 + h) * 2 + 0) * 16;
        const float* pb1 = PB + ((L * 2 + h) * 2 + 1) * 16;
#pragma unroll
        for (int r = 0; r < 16; ++r) {
            acc[0][r] = pb0[r];
            acc[1][r] = pb1[r];
        }

        const unsigned short* aL = ldsA + L * L_STRIDE;
#pragma unroll
        for (int s = 0; s < 4; ++s) {
            const unsigned short* base = aL + s * S_STRIDE + lane * T_STRIDE;
            short8 ah0 = *(const short8*)(base + 0 * M_STRIDE + 0 * PART_STRIDE);
            short8 al0 = *(const short8*)(base + 0 * M_STRIDE + 1 * PART_STRIDE);
            short8 ah1 = *(const short8*)(base + 1 * M_STRIDE + 0 * PART_STRIDE);
            short8 al1 = *(const short8*)(base + 1 * M_STRIDE + 1 * PART_STRIDE);
            acc[0] = __builtin_amdgcn_mfma_f32_32x32x16_bf16(ah0, Bhi[s].s, acc[0], 0, 0, 0);
            acc[1] = __builtin_amdgcn_mfma_f32_32x32x16_bf16(ah1, Bhi[s].s, acc[1], 0, 0, 0);
            acc[0] = __builtin_amdgcn_mfma_f32_32x32x16_bf16(ah0, Blo[s].s, acc[0], 0, 0, 0);
            acc[1] = __builtin_amdgcn_mfma_f32_32x32x16_bf16(ah1, Blo[s].s, acc[1], 0, 0, 0);
            acc[0] = __builtin_amdgcn_mfma_f32_32x32x16_bf16(al0, Bhi[s].s, acc[0], 0, 0, 0);
            acc[1] = __builtin_amdgcn_mfma_f32_32x32x16_bf16(al1, Bhi[s].s, acc[1], 0, 0, 0);
        }

        if (L < 3) {
            // in-place C->B: B slot (s2,h,t=2j,2j+1) <- acc[s2>>1][2j+8(s2&1)(+1)]
#pragma unroll
            for (int s2 = 0; s2 < 4; ++s2) {
                const int m = s2 >> 1;
                const int rb = 8 * (s2 & 1);
#pragma unroll
                for (int j = 0; j < 4; ++j) {
                    float h0 = silu_l2(acc[m][rb + 2 * j]);
                    float h1 = silu_l2(acc[m][rb + 2 * j + 1]);
                    unsigned hd, ld;
                    split_pair(h0, h1, hd, ld);
                    Bhi[s2].i[j] = (int)hd;
                    Blo[s2].i[j] = (int)ld;
                }
            }
        } else {
            // ---- output layer: SiLU then dot with prepped Wout (ln2-scaled),
            // reduce the two k-halves across h.
            const float* pw0 = PW + (h * 2 + 0) * 16;
            const float* pw1 = PW + (h * 2 + 1) * 16;
            float dot = 0.0f;
#pragma unroll
            for (int r = 0; r < 16; ++r) {
                dot = fmaf(silu_l2(acc[0][r]), pw0[r], dot);
                dot = fmaf(silu_l2(acc[1][r]), pw1[r], dot);
            }
            dot += __shfl_xor(dot, 32);
            if (h == 0 && row < n) out[row] = dot + bout[0];
        }
    }
}

extern "C" void kernel_launch(void* const* d_in, const int* in_sizes, int n_in,
                              void* d_out, int out_size, void* d_ws, size_t ws_size,
                              hipStream_t stream) {
    const float* x    = (const float*)d_in[0];
    const float* W0   = (const float*)d_in[1];
    const float* b0   = (const float*)d_in[2];
    const float* W1   = (const float*)d_in[3];
    const float* b1   = (const float*)d_in[4];
    const float* W2   = (const float*)d_in[5];
    const float* b2   = (const float*)d_in[6];
    const float* W3   = (const float*)d_in[7];
    const float* b3   = (const float*)d_in[8];
    const float* W4   = (const float*)d_in[9];
    const float* b4   = (const float*)d_in[10];
    const float* Wout = (const float*)d_in[11];
    const float* bout = (const float*)d_in[12];
    float* out = (float*)d_out;

    int n = in_sizes[0];  // 2,097,152 (divisible by 256)
    int grid = (n + 255) / 256;

    prep_kernel<<<16, 256, 0, stream>>>(W0, b0, W1, W2, W3, W4,
                                        b1, b2, b3, b4, Wout,
                                        (unsigned char*)d_ws);
    mlp_mfma<<<grid, 512, 0, stream>>>(x, bout,
                                       (const unsigned char*)d_ws, out, n);
}